// Round 18
// baseline (272.637 us; speedup 1.0000x reference)
//
#include <hip/hip_runtime.h>
#include <hip/hip_bf16.h>
#include <stdint.h>

#define NB 4096
#define NCOL 100
#define NCOND 64
#define NTOTAL 6400
#define NRODT 1600
#define NEST 160
#define NFOR 100
#define NHID 128
#define NCLS 10
#define GEPS 1e-5f

typedef __attribute__((ext_vector_type(8))) short short8;
typedef __attribute__((ext_vector_type(4))) float floatx4;

// round-half-up f32->bf16: 2 VALU ops; tie-only difference vs RNE
__device__ __forceinline__ unsigned f2bfu(float x) {
  union { float f; unsigned u; } v; v.f = x;
  return (v.u + 0x8000u) >> 16;
}
__device__ __forceinline__ float bf2f(unsigned short u) {
  union { unsigned u; float f; } v; v.u = ((unsigned)u) << 16;
  return v.f;
}

// all-reduce sum over the 16-lane DPP row -- VALU pipe, no LDS.
__device__ __forceinline__ float rowsum16(float v) {
  union { float f; int i; } a, t;
  a.f = v;
  t.i = __builtin_amdgcn_update_dpp(0, a.i, 0x128, 0xf, 0xf, true); a.f += t.f; // ror:8
  t.i = __builtin_amdgcn_update_dpp(0, a.i, 0x124, 0xf, 0xf, true); a.f += t.f; // ror:4
  t.i = __builtin_amdgcn_update_dpp(0, a.i, 0x122, 0xf, 0xf, true); a.f += t.f; // ror:2
  t.i = __builtin_amdgcn_update_dpp(0, a.i, 0x121, 0xf, 0xf, true); a.f += t.f; // ror:1
  return a.f;
}

// ---------------------------------------------------------------------------
// K01: merged prep kernel (single launch).  Identical to R17 (proven).
//  blocks [0,1600)    : k1 -- ConditionGeneration+perm+phi_2 -> wT[g][b] bf16
//  blocks [1600,1702) : k0 -- fragment-pack Bf / W1f / W2f (identity k-map)
//  blocks [1702,1705) : zero d_out
// ---------------------------------------------------------------------------
__global__ __launch_bounds__(256) void k01_prep(
    const float* __restrict__ x, const float* __restrict__ w1,
    const float* __restrict__ b1, const int* __restrict__ perm,
    const float* __restrict__ gn1w, const float* __restrict__ gn1b,
    const float* __restrict__ c2w, const float* __restrict__ c2b,
    const float* __restrict__ gn2w, const float* __restrict__ gn2b,
    const float* __restrict__ c3w, const float* __restrict__ c3b,
    const float* __restrict__ E, const int* __restrict__ swr,
    const float* __restrict__ fc1w, const float* __restrict__ fc2w,
    unsigned short* __restrict__ wT,
    unsigned short* __restrict__ Bf, unsigned short* __restrict__ W1f,
    unsigned short* __restrict__ W2f, float* __restrict__ out)
{
  __shared__ float xl[64 * NCOL];          // k1 path only (25.6 KB)
  __shared__ int ridx[NEST];               // k0 path only
  const int tid = threadIdx.x;
  const int blk = blockIdx.x;

  if (blk < 1600) {
    // ---------------- k1: phi_2 logits -> bf16, transposed ----------------
    const int b0 = (blk & 63) * 64;
    const int g  = (blk >> 6) * 64 + (tid >> 2);
    const int i4 = tid & 3;
    for (int i = tid; i < 64 * NCOL; i += 256)
      xl[i] = x[(size_t)b0 * NCOL + i];
    __syncthreads();

    const int4 p4 = *(const int4*)(perm + 4 * g);
    const int pv[4] = {p4.x, p4.y, p4.z, p4.w};
    float w1v[4], b1v[4];
    int pc[4];
#pragma unroll
    for (int i = 0; i < 4; i++) {
      unsigned p = (unsigned)pv[i];
      unsigned j = p / 100u;
      unsigned cc = p - j * 100u;
      pc[i] = (int)cc;
      w1v[i] = w1[cc * NCOND + j];
      b1v[i] = b1[cc * NCOND + j];
    }
    const float4 g1w = *(const float4*)(gn1w + 4 * g);
    const float4 g1b = *(const float4*)(gn1b + 4 * g);
    const float4 cw0 = *(const float4*)(c2w + 16 * g);
    const float4 cw1 = *(const float4*)(c2w + 16 * g + 4);
    const float4 cw2 = *(const float4*)(c2w + 16 * g + 8);
    const float4 cw3 = *(const float4*)(c2w + 16 * g + 12);
    const float4 cbv = *(const float4*)(c2b + 4 * g);
    const float4 g2w = *(const float4*)(gn2w + 4 * g);
    const float4 g2b = *(const float4*)(gn2b + 4 * g);
    const float4 c3v = *(const float4*)(c3w + 4 * g);
    const float c3bv = c3b[g];

    for (int k = 0; k < 4; k++) {
      float v4[4];
#pragma unroll
      for (int j = 0; j < 4; j++) {
        const int bb = k * 16 + i4 * 4 + j;
        float O[4];
#pragma unroll
        for (int i = 0; i < 4; i++) {
          float a = xl[bb * NCOL + pc[i]] * w1v[i] + b1v[i];
          O[i] = 1.0f / (1.0f + __expf(-a));
        }
        float mu = 0.25f * (O[0] + O[1] + O[2] + O[3]);
        float d[4], var = 0.f;
#pragma unroll
        for (int i = 0; i < 4; i++) { d[i] = O[i] - mu; var += d[i] * d[i]; }
        float rs = rsqrtf(0.25f * var + GEPS);
        float xn0 = d[0] * rs * g1w.x + g1b.x;
        float xn1 = d[1] * rs * g1w.y + g1b.y;
        float xn2 = d[2] * rs * g1w.z + g1b.z;
        float xn3 = d[3] * rs * g1w.w + g1b.w;
        float h[4];
        h[0] = xn0*cw0.x + xn1*cw1.x + xn2*cw2.x + xn3*cw3.x + cbv.x;
        h[1] = xn0*cw0.y + xn1*cw1.y + xn2*cw2.y + xn3*cw3.y + cbv.y;
        h[2] = xn0*cw0.z + xn1*cw1.z + xn2*cw2.z + xn3*cw3.z + cbv.z;
        h[3] = xn0*cw0.w + xn1*cw1.w + xn2*cw2.w + xn3*cw3.w + cbv.w;
#pragma unroll
        for (int i = 0; i < 4; i++) h[i] = fmaxf(h[i], 0.f);
        float mu2 = 0.25f * (h[0] + h[1] + h[2] + h[3]);
        float e[4], var2 = 0.f;
#pragma unroll
        for (int i = 0; i < 4; i++) { e[i] = h[i] - mu2; var2 += e[i] * e[i]; }
        float rs2 = rsqrtf(0.25f * var2 + GEPS);
        float hn0 = e[0] * rs2 * g2w.x + g2b.x;
        float hn1 = e[1] * rs2 * g2w.y + g2b.y;
        float hn2 = e[2] * rs2 * g2w.z + g2b.z;
        float hn3 = e[3] * rs2 * g2w.w + g2b.w;
        v4[j] = hn0*c3v.x + hn1*c3v.y + hn2*c3v.z + hn3*c3v.w + c3bv;
      }
      uint2 pk;
      pk.x = f2bfu(v4[0]) | (f2bfu(v4[1]) << 16);
      pk.y = f2bfu(v4[2]) | (f2bfu(v4[3]) << 16);
      *(uint2*)(wT + (size_t)g * NB + b0 + k * 16 + i4 * 4) = pk;
    }
  } else if (blk < 1600 + NFOR) {
    // ---------------- k0: Bf fragment pack ----------------
    const int fblk = blk - 1600;
    if (tid < NEST) ridx[tid] = swr[fblk * NEST + tid];
    __syncthreads();
    for (int m = tid; m < 2560; m += 256) {        // m = (n*5+kc)*64 + lane
      int lane = m & 63, rest = m >> 6;
      int kc = rest % 5, n = rest / 5;
      int q = lane >> 4, c = lane & 15;
      int e0 = kc * 32 + q * 8;
      int h = n * 16 + c;
      union { unsigned short v[8]; uint4 u; } t;
#pragma unroll
      for (int j = 0; j < 8; j++)
        t.v[j] = (unsigned short)f2bfu(E[(size_t)ridx[e0 + j] * NHID + h]);
      *(uint4*)(Bf + (size_t)fblk * 20480 + (size_t)m * 8) = t.u;
    }
  } else if (blk == 1600 + NFOR) {
    // ---------------- k0: W1f (identity k-map) ----------------
    for (int m = tid; m < 2048; m += 256) {        // m = (n*4+kc)*64 + lane
      int lane = m & 63, rest = m >> 6;
      int kc = rest & 3, n = rest >> 2;
      int q = lane >> 4, c = lane & 15;
      int k0 = kc * 32 + q * 8;
      int o = n * 16 + c;
      union { unsigned short v[8]; uint4 u; } t;
#pragma unroll
      for (int j = 0; j < 8; j++)
        t.v[j] = (unsigned short)f2bfu(fc1w[(size_t)(k0 + j) * NHID + o]);
      *(uint4*)(W1f + (size_t)m * 8) = t.u;
    }
  } else if (blk == 1601 + NFOR) {
    // ---------------- k0: W2f (identity k-map) ----------------
    for (int m = tid; m < 256; m += 256) {         // m = kc*64 + lane
      int lane = m & 63, kc = m >> 6;
      int q = lane >> 4, c = lane & 15;
      int k0 = kc * 32 + q * 8;
      union { unsigned short v[8]; uint4 u; } t;
#pragma unroll
      for (int j = 0; j < 8; j++)
        t.v[j] = (unsigned short)f2bfu(c < NCLS ? fc2w[(size_t)(k0 + j) * NCLS + c] : 0.f);
      *(uint4*)(W2f + (size_t)m * 8) = t.u;
    }
  } else {
    // ---------------- zero d_out (3 blocks) ----------------
    const int z = blk - (1602 + NFOR);
    float4 zz = make_float4(0.f, 0.f, 0.f, 0.f);
    for (int i = z * 256 + tid; i < NB * NCLS / 4; i += 3 * 256)
      ((float4*)out)[i] = zz;
  }
}

// ---------------------------------------------------------------------------
// K3: BARRIER-FREE gather+softmax+MFMA pipeline.
// Gather ownership remap: lane=(r4=lane>>2, ch=lane&3); thread gathers the
// 40 e-values of chunk ch for row wv*16+r4.  Every lsA row is wave-private
// for its whole lifetime -> NO __syncthreads anywhere; each wave enters
// GEMM1 as soon as its own gather lands.  Softmax sum: 40-value partial +
// shfl_xor(1,2) over chunk lanes; LN1 fetches st per row via one __shfl.
// Indices: per-lane int4 pairs per batch (L1-hot), fully unrolled.
// ---------------------------------------------------------------------------
__global__ __launch_bounds__(256, 6) void k3_mfma(
    const unsigned short* __restrict__ wT,    // [1600][B] bf16 logits^T
    const int* __restrict__ swr,
    const unsigned short* __restrict__ Bf,    // [f][8][5][64][8]
    const unsigned short* __restrict__ W1f,   // [8][4][64][8]
    const unsigned short* __restrict__ W2f,   // [4][64][8]
    const float* __restrict__ ln1w, const float* __restrict__ ln1b,
    const float* __restrict__ fc1b,
    const float* __restrict__ ln2w, const float* __restrict__ ln2b,
    const float* __restrict__ fc2b,
    float* __restrict__ out)
{
  __shared__ unsigned short lsA[64 * 168];    // 21504 B (only LDS)

  const int tid = threadIdx.x;
  const int b0 = blockIdx.x * 64;
  const int f  = blockIdx.y;
  const int lane = tid & 63;
  const int wv = __builtin_amdgcn_readfirstlane(tid >> 6);  // wave-uniform SGPR
  const int c = lane & 15, q = lane >> 4;

  // ---- gather + exp: thread (r4,ch) owns row wv*16+r4, e in [40ch,40ch+40) ----
  float st;   // full softmax sum for row r4 (all 4 chunk lanes hold it)
  {
    const int r4 = lane >> 2, ch = lane & 3;
    const unsigned short* wbase = wT + b0 + wv * 16 + r4;
    const int4* ip = (const int4*)(swr + f * NEST + ch * 40);
    unsigned short* arow = lsA + (wv * 16 + r4) * 168 + ch * 40;
    float ssum = 0.f;
#pragma unroll
    for (int k = 0; k < 5; k++) {
      int4 ia = ip[2 * k], ib = ip[2 * k + 1];
      int id8[8] = {ia.x, ia.y, ia.z, ia.w, ib.x, ib.y, ib.z, ib.w};
      unsigned us[8];
#pragma unroll
      for (int jj = 0; jj < 8; jj++) {
        float v = bf2f(wbase[(size_t)id8[jj] * NB]);
        float ex = __expf(v);
        ssum += ex;
        us[jj] = f2bfu(ex);
      }
      uint4 pk = {us[0] | (us[1] << 16), us[2] | (us[3] << 16),
                  us[4] | (us[5] << 16), us[6] | (us[7] << 16)};
      *(uint4*)(arow + k * 8) = pk;
    }
    ssum += __shfl_xor(ssum, 1);
    ssum += __shfl_xor(ssum, 2);
    st = ssum;
  }
  // NO barrier: all lsA rows wave-private; per-wave DS ordering suffices.

  // ---- GEMM1: (exp-ws)[64x160] @ Ep[160x128]  (kc-outer) ----
  const unsigned short* pa = lsA + (wv * 16 + c) * 168 + q * 8;
  floatx4 acc[8];
#pragma unroll
  for (int n = 0; n < 8; n++) acc[n] = (floatx4){0.f, 0.f, 0.f, 0.f};

  const unsigned short* bbase = Bf + (size_t)f * 20480 + lane * 8;
#pragma unroll
  for (int kc = 0; kc < 5; kc++) {
    short8 a = *(const short8*)(pa + kc * 32);
#pragma unroll
    for (int n = 0; n < 8; n++) {
      short8 b = *(const short8*)(bbase + n * 2560 + kc * 512);
      acc[n] = __builtin_amdgcn_mfma_f32_16x16x32_bf16(a, b, acc[n], 0, 0, 0);
    }
  }

  // ---- LN1 with softmax fold: LN(x/s) == (x-mu)*rsqrt(var + eps*s^2) ----
  {
    float lw[8], lb[8];
#pragma unroll
    for (int n = 0; n < 8; n++) { lw[n] = ln1w[n * 16 + c]; lb[n] = ln1b[n * 16 + c]; }
#pragma unroll
    for (int rr = 0; rr < 4; rr++) {
      const float strow = __shfl(st, (q * 4 + rr) * 4);   // st for row q*4+rr
      float s1 = 0.f, s2 = 0.f;
#pragma unroll
      for (int n = 0; n < 8; n++) { float v = acc[n][rr]; s1 += v; s2 += v * v; }
      s1 = rowsum16(s1);
      s2 = rowsum16(s2);
      float mu = s1 * (1.f / 128.f);
      float var = fmaxf(s2 * (1.f / 128.f) - mu * mu, 0.f);
      float rs = rsqrtf(var + GEPS * strow * strow);
#pragma unroll
      for (int n = 0; n < 8; n++)
        acc[n][rr] = (acc[n][rr] - mu) * rs * lw[n] + lb[n];
    }
  }

  // ---- Fn -> lsA (A-layout bf16, wave-private; no barrier) ----
#pragma unroll
  for (int rr = 0; rr < 4; rr++)
#pragma unroll
    for (int n = 0; n < 8; n++)
      lsA[(wv * 16 + q * 4 + rr) * 168 + n * 16 + c] =
          (unsigned short)f2bfu(acc[n][rr]);

  // ---- GEMM2: H = Fn[64x128] @ fc1w[128x128]  (kc-outer) ----
  {
    short8 a0 = *(const short8*)(pa);
    short8 a1 = *(const short8*)(pa + 32);
    short8 a2 = *(const short8*)(pa + 64);
    short8 a3 = *(const short8*)(pa + 96);
#pragma unroll
    for (int n = 0; n < 8; n++) acc[n] = (floatx4){0.f, 0.f, 0.f, 0.f};
    const unsigned short* w1p = W1f + lane * 8;
#pragma unroll
    for (int n = 0; n < 8; n++) {
      const unsigned short* wp = w1p + n * 2048;
      acc[n] = __builtin_amdgcn_mfma_f32_16x16x32_bf16(a0, *(const short8*)(wp),        acc[n], 0, 0, 0);
      acc[n] = __builtin_amdgcn_mfma_f32_16x16x32_bf16(a1, *(const short8*)(wp + 512),  acc[n], 0, 0, 0);
      acc[n] = __builtin_amdgcn_mfma_f32_16x16x32_bf16(a2, *(const short8*)(wp + 1024), acc[n], 0, 0, 0);
      acc[n] = __builtin_amdgcn_mfma_f32_16x16x32_bf16(a3, *(const short8*)(wp + 1536), acc[n], 0, 0, 0);
    }
  }

  // ---- bias + ReLU + LN2 (DPP row-reduce) ----
  {
    float fb[8], lw[8], lb[8];
#pragma unroll
    for (int n = 0; n < 8; n++) {
      fb[n] = fc1b[n * 16 + c];
      lw[n] = ln2w[n * 16 + c]; lb[n] = ln2b[n * 16 + c];
    }
#pragma unroll
    for (int rr = 0; rr < 4; rr++) {
#pragma unroll
      for (int n = 0; n < 8; n++) acc[n][rr] = fmaxf(acc[n][rr] + fb[n], 0.f);
      float s1 = 0.f, s2 = 0.f;
#pragma unroll
      for (int n = 0; n < 8; n++) { float v = acc[n][rr]; s1 += v; s2 += v * v; }
      s1 = rowsum16(s1);
      s2 = rowsum16(s2);
      float mu = s1 * (1.f / 128.f);
      float var = fmaxf(s2 * (1.f / 128.f) - mu * mu, 0.f);
      float rs = rsqrtf(var + GEPS);
#pragma unroll
      for (int n = 0; n < 8; n++)
        acc[n][rr] = (acc[n][rr] - mu) * rs * lw[n] + lb[n];
    }
  }

  // ---- H2 -> lsA (A-layout, wave-private; no barrier) ----
#pragma unroll
  for (int rr = 0; rr < 4; rr++)
#pragma unroll
    for (int n = 0; n < 8; n++)
      lsA[(wv * 16 + q * 4 + rr) * 168 + n * 16 + c] =
          (unsigned short)f2bfu(acc[n][rr]);

  // ---- fc2 (16-col padded tile) + mean-atomic ----
  floatx4 o4 = (floatx4){0.f, 0.f, 0.f, 0.f};
#pragma unroll
  for (int kc = 0; kc < 4; kc++) {
    short8 a = *(const short8*)(pa + kc * 32);
    short8 b = *(const short8*)(W2f + kc * 512 + lane * 8);
    o4 = __builtin_amdgcn_mfma_f32_16x16x32_bf16(a, b, o4, 0, 0, 0);
  }
  if (c < NCLS) {
    float bias = fc2b[c];
#pragma unroll
    for (int rr = 0; rr < 4; rr++)
      atomicAdd(out + (size_t)(b0 + wv * 16 + q * 4 + rr) * NCLS + c,
                (o4[rr] + bias) * 0.01f);
  }
}

// ---------------------------------------------------------------------------
extern "C" void kernel_launch(void* const* d_in, const int* in_sizes, int n_in,
                              void* d_out, int out_size, void* d_ws, size_t ws_size,
                              hipStream_t stream)
{
  (void)in_sizes; (void)n_in; (void)ws_size; (void)out_size;
  const float* x    = (const float*)d_in[0];
  const float* w1   = (const float*)d_in[1];
  const float* b1   = (const float*)d_in[2];
  const int*   perm = (const int*)d_in[3];
  const float* gn1w = (const float*)d_in[4];
  const float* gn1b = (const float*)d_in[5];
  const float* c2w  = (const float*)d_in[6];
  const float* c2b  = (const float*)d_in[7];
  const float* gn2w = (const float*)d_in[8];
  const float* gn2b = (const float*)d_in[9];
  const float* c3w  = (const float*)d_in[10];
  const float* c3b  = (const float*)d_in[11];
  const int*   swr  = (const int*)d_in[12];
  const float* E    = (const float*)d_in[13];
  const float* ln1w = (const float*)d_in[14];
  const float* ln1b = (const float*)d_in[15];
  const float* fc1w = (const float*)d_in[16];
  const float* fc1b = (const float*)d_in[17];
  const float* ln2w = (const float*)d_in[18];
  const float* ln2b = (const float*)d_in[19];
  const float* fc2w = (const float*)d_in[20];
  const float* fc2b = (const float*)d_in[21];
  float* out = (float*)d_out;

  // workspace layout:
  //   [0, 13.1MB)       : wT logits bf16 [1600][B]
  //   [13.1MB, +4.10MB) : Bf (100*20480 shorts)
  //   then W1f 32,768 B, W2f 4,096 B
  const size_t W_BYTES = (size_t)NB * NRODT * 2;     // 13,107,200
  unsigned short* wTbuf = (unsigned short*)d_ws;
  unsigned short* Bfb   = (unsigned short*)((char*)d_ws + W_BYTES);
  unsigned short* W1fb  = (unsigned short*)((char*)d_ws + W_BYTES + 4096000);
  unsigned short* W2fb  = (unsigned short*)((char*)d_ws + W_BYTES + 4096000 + 32768);

  k01_prep<<<1600 + NFOR + 2 + 3, 256, 0, stream>>>(
      x, w1, b1, perm, gn1w, gn1b, c2w, c2b, gn2w, gn2b, c3w, c3b,
      E, swr, fc1w, fc2w, wTbuf, Bfb, W1fb, W2fb, out);
  dim3 g3(NB / 64, NFOR);
  k3_mfma<<<g3, 256, 0, stream>>>(wTbuf, swr, Bfb, W1fb, W2fb,
                                  ln1w, ln1b, fc1b, ln2w, ln2b, fc2b, out);
}

// Round 19
// 217.660 us; speedup vs baseline: 1.2526x; 1.2526x over previous
//
#include <hip/hip_runtime.h>
#include <hip/hip_bf16.h>
#include <stdint.h>

#define NB 4096
#define NCOL 100
#define NCOND 64
#define NTOTAL 6400
#define NRODT 1600
#define NEST 160
#define NFOR 100
#define NHID 128
#define NCLS 10
#define GEPS 1e-5f

typedef __attribute__((ext_vector_type(8))) short short8;
typedef __attribute__((ext_vector_type(4))) float floatx4;

// round-half-up f32->bf16: 2 VALU ops; tie-only difference vs RNE
__device__ __forceinline__ unsigned f2bfu(float x) {
  union { float f; unsigned u; } v; v.f = x;
  return (v.u + 0x8000u) >> 16;
}
__device__ __forceinline__ float bf2f(unsigned short u) {
  union { unsigned u; float f; } v; v.u = ((unsigned)u) << 16;
  return v.f;
}

// all-reduce sum over the 16-lane DPP row -- VALU pipe, no LDS.
__device__ __forceinline__ float rowsum16(float v) {
  union { float f; int i; } a, t;
  a.f = v;
  t.i = __builtin_amdgcn_update_dpp(0, a.i, 0x128, 0xf, 0xf, true); a.f += t.f; // ror:8
  t.i = __builtin_amdgcn_update_dpp(0, a.i, 0x124, 0xf, 0xf, true); a.f += t.f; // ror:4
  t.i = __builtin_amdgcn_update_dpp(0, a.i, 0x122, 0xf, 0xf, true); a.f += t.f; // ror:2
  t.i = __builtin_amdgcn_update_dpp(0, a.i, 0x121, 0xf, 0xf, true); a.f += t.f; // ror:1
  return a.f;
}

// ---------------------------------------------------------------------------
// K01: merged prep kernel (single launch).
//  blocks [0,1600)    : k1 -- ConditionGeneration+perm+phi_2 -> wT[g][b] bf16
//  blocks [1600,1702) : k0 -- fragment-pack Bf / W1f / W2f (identity k-map)
//  blocks [1702,1705) : zero d_out
// ---------------------------------------------------------------------------
__global__ __launch_bounds__(256) void k01_prep(
    const float* __restrict__ x, const float* __restrict__ w1,
    const float* __restrict__ b1, const int* __restrict__ perm,
    const float* __restrict__ gn1w, const float* __restrict__ gn1b,
    const float* __restrict__ c2w, const float* __restrict__ c2b,
    const float* __restrict__ gn2w, const float* __restrict__ gn2b,
    const float* __restrict__ c3w, const float* __restrict__ c3b,
    const float* __restrict__ E, const int* __restrict__ swr,
    const float* __restrict__ fc1w, const float* __restrict__ fc2w,
    unsigned short* __restrict__ wT,
    unsigned short* __restrict__ Bf, unsigned short* __restrict__ W1f,
    unsigned short* __restrict__ W2f, float* __restrict__ out)
{
  __shared__ float xl[64 * NCOL];          // k1 path only (25.6 KB)
  __shared__ int ridx[NEST];               // k0 path only
  const int tid = threadIdx.x;
  const int blk = blockIdx.x;

  if (blk < 1600) {
    // ---------------- k1: phi_2 logits -> bf16, transposed ----------------
    const int b0 = (blk & 63) * 64;
    const int g  = (blk >> 6) * 64 + (tid >> 2);
    const int i4 = tid & 3;
    for (int i = tid; i < 64 * NCOL; i += 256)
      xl[i] = x[(size_t)b0 * NCOL + i];
    __syncthreads();

    const int4 p4 = *(const int4*)(perm + 4 * g);
    const int pv[4] = {p4.x, p4.y, p4.z, p4.w};
    float w1v[4], b1v[4];
    int pc[4];
#pragma unroll
    for (int i = 0; i < 4; i++) {
      unsigned p = (unsigned)pv[i];
      unsigned j = p / 100u;
      unsigned cc = p - j * 100u;
      pc[i] = (int)cc;
      w1v[i] = w1[cc * NCOND + j];
      b1v[i] = b1[cc * NCOND + j];
    }
    const float4 g1w = *(const float4*)(gn1w + 4 * g);
    const float4 g1b = *(const float4*)(gn1b + 4 * g);
    const float4 cw0 = *(const float4*)(c2w + 16 * g);
    const float4 cw1 = *(const float4*)(c2w + 16 * g + 4);
    const float4 cw2 = *(const float4*)(c2w + 16 * g + 8);
    const float4 cw3 = *(const float4*)(c2w + 16 * g + 12);
    const float4 cbv = *(const float4*)(c2b + 4 * g);
    const float4 g2w = *(const float4*)(gn2w + 4 * g);
    const float4 g2b = *(const float4*)(gn2b + 4 * g);
    const float4 c3v = *(const float4*)(c3w + 4 * g);
    const float c3bv = c3b[g];

    for (int k = 0; k < 4; k++) {
      float v4[4];
#pragma unroll
      for (int j = 0; j < 4; j++) {
        const int bb = k * 16 + i4 * 4 + j;
        float O[4];
#pragma unroll
        for (int i = 0; i < 4; i++) {
          float a = xl[bb * NCOL + pc[i]] * w1v[i] + b1v[i];
          O[i] = 1.0f / (1.0f + __expf(-a));
        }
        float mu = 0.25f * (O[0] + O[1] + O[2] + O[3]);
        float d[4], var = 0.f;
#pragma unroll
        for (int i = 0; i < 4; i++) { d[i] = O[i] - mu; var += d[i] * d[i]; }
        float rs = rsqrtf(0.25f * var + GEPS);
        float xn0 = d[0] * rs * g1w.x + g1b.x;
        float xn1 = d[1] * rs * g1w.y + g1b.y;
        float xn2 = d[2] * rs * g1w.z + g1b.z;
        float xn3 = d[3] * rs * g1w.w + g1b.w;
        float h[4];
        h[0] = xn0*cw0.x + xn1*cw1.x + xn2*cw2.x + xn3*cw3.x + cbv.x;
        h[1] = xn0*cw0.y + xn1*cw1.y + xn2*cw2.y + xn3*cw3.y + cbv.y;
        h[2] = xn0*cw0.z + xn1*cw1.z + xn2*cw2.z + xn3*cw3.z + cbv.z;
        h[3] = xn0*cw0.w + xn1*cw1.w + xn2*cw2.w + xn3*cw3.w + cbv.w;
#pragma unroll
        for (int i = 0; i < 4; i++) h[i] = fmaxf(h[i], 0.f);
        float mu2 = 0.25f * (h[0] + h[1] + h[2] + h[3]);
        float e[4], var2 = 0.f;
#pragma unroll
        for (int i = 0; i < 4; i++) { e[i] = h[i] - mu2; var2 += e[i] * e[i]; }
        float rs2 = rsqrtf(0.25f * var2 + GEPS);
        float hn0 = e[0] * rs2 * g2w.x + g2b.x;
        float hn1 = e[1] * rs2 * g2w.y + g2b.y;
        float hn2 = e[2] * rs2 * g2w.z + g2b.z;
        float hn3 = e[3] * rs2 * g2w.w + g2b.w;
        v4[j] = hn0*c3v.x + hn1*c3v.y + hn2*c3v.z + hn3*c3v.w + c3bv;
      }
      uint2 pk;
      pk.x = f2bfu(v4[0]) | (f2bfu(v4[1]) << 16);
      pk.y = f2bfu(v4[2]) | (f2bfu(v4[3]) << 16);
      *(uint2*)(wT + (size_t)g * NB + b0 + k * 16 + i4 * 4) = pk;
    }
  } else if (blk < 1600 + NFOR) {
    // ---------------- k0: Bf fragment pack ----------------
    const int fblk = blk - 1600;
    if (tid < NEST) ridx[tid] = swr[fblk * NEST + tid];
    __syncthreads();
    for (int m = tid; m < 2560; m += 256) {        // m = (n*5+kc)*64 + lane
      int lane = m & 63, rest = m >> 6;
      int kc = rest % 5, n = rest / 5;
      int q = lane >> 4, c = lane & 15;
      int e0 = kc * 32 + q * 8;
      int h = n * 16 + c;
      union { unsigned short v[8]; uint4 u; } t;
#pragma unroll
      for (int j = 0; j < 8; j++)
        t.v[j] = (unsigned short)f2bfu(E[(size_t)ridx[e0 + j] * NHID + h]);
      *(uint4*)(Bf + (size_t)fblk * 20480 + (size_t)m * 8) = t.u;
    }
  } else if (blk == 1600 + NFOR) {
    // ---------------- k0: W1f (identity k-map) ----------------
    for (int m = tid; m < 2048; m += 256) {        // m = (n*4+kc)*64 + lane
      int lane = m & 63, rest = m >> 6;
      int kc = rest & 3, n = rest >> 2;
      int q = lane >> 4, c = lane & 15;
      int k0 = kc * 32 + q * 8;
      int o = n * 16 + c;
      union { unsigned short v[8]; uint4 u; } t;
#pragma unroll
      for (int j = 0; j < 8; j++)
        t.v[j] = (unsigned short)f2bfu(fc1w[(size_t)(k0 + j) * NHID + o]);
      *(uint4*)(W1f + (size_t)m * 8) = t.u;
    }
  } else if (blk == 1601 + NFOR) {
    // ---------------- k0: W2f (identity k-map) ----------------
    for (int m = tid; m < 256; m += 256) {         // m = kc*64 + lane
      int lane = m & 63, kc = m >> 6;
      int q = lane >> 4, c = lane & 15;
      int k0 = kc * 32 + q * 8;
      union { unsigned short v[8]; uint4 u; } t;
#pragma unroll
      for (int j = 0; j < 8; j++)
        t.v[j] = (unsigned short)f2bfu(c < NCLS ? fc2w[(size_t)(k0 + j) * NCLS + c] : 0.f);
      *(uint4*)(W2f + (size_t)m * 8) = t.u;
    }
  } else {
    // ---------------- zero d_out (3 blocks) ----------------
    const int z = blk - (1602 + NFOR);
    float4 zz = make_float4(0.f, 0.f, 0.f, 0.f);
    for (int i = z * 256 + tid; i < NB * NCLS / 4; i += 3 * 256)
      ((float4*)out)[i] = zz;
  }
}

// ---------------------------------------------------------------------------
// K3: streaming-gather softmax + MFMA pipeline (R17, measured best).
//  - coalesced gather: lanes = b (64 consecutive bf16 = 2 lines/instr)
//  - swr indices via wave-uniform scalar loads; LN reductions on DPP
//  - softmax 1/s folded into LN1's eps; ONE barrier
//  - sPT transposed [64][4]: partial reads are 1 ds_read_b128/row
// ---------------------------------------------------------------------------
__global__ __launch_bounds__(256, 6) void k3_mfma(
    const unsigned short* __restrict__ wT,    // [1600][B] bf16 logits^T
    const int* __restrict__ swr,
    const unsigned short* __restrict__ Bf,    // [f][8][5][64][8]
    const unsigned short* __restrict__ W1f,   // [8][4][64][8]
    const unsigned short* __restrict__ W2f,   // [4][64][8]
    const float* __restrict__ ln1w, const float* __restrict__ ln1b,
    const float* __restrict__ fc1b,
    const float* __restrict__ ln2w, const float* __restrict__ ln2b,
    const float* __restrict__ fc2b,
    float* __restrict__ out)
{
  __shared__ unsigned short lsA[64 * 168];    // 21504 B
  __shared__ __align__(16) float sPT[64][4];  // per-row wave partials (transposed)

  const int tid = threadIdx.x;
  const int b0 = blockIdx.x * 64;
  const int f  = blockIdx.y;
  const int lane = tid & 63;
  const int wv = __builtin_amdgcn_readfirstlane(tid >> 6);  // wave-uniform SGPR
  const int c = lane & 15, q = lane >> 4;

  // ---- gather + exp phase: wave wv covers e in [40wv, 40wv+40) ----
  {
    const unsigned short* wbase = wT + b0 + lane;
    const int* swf = swr + f * NEST + wv * 40;   // wave-uniform -> s_load
    float ssum = 0.f;
#pragma unroll
    for (int k = 0; k < 5; k++) {
      int id8[8];
#pragma unroll
      for (int jj = 0; jj < 8; jj++) id8[jj] = swf[k * 8 + jj];
      unsigned us[8];
#pragma unroll
      for (int jj = 0; jj < 8; jj++) {
        float v = bf2f(wbase[(size_t)id8[jj] * NB]);
        float ex = __expf(v);
        ssum += ex;
        us[jj] = f2bfu(ex);
      }
      uint4 pk = {us[0] | (us[1] << 16), us[2] | (us[3] << 16),
                  us[4] | (us[5] << 16), us[6] | (us[7] << 16)};
      *(uint4*)(lsA + lane * 168 + wv * 40 + k * 8) = pk;
    }
    sPT[lane][wv] = ssum;
  }
  __syncthreads();                     // the ONLY barrier

  // ---- GEMM1: (exp-ws)[64x160] @ Ep[160x128]  (kc-outer) ----
  const unsigned short* pa = lsA + (wv * 16 + c) * 168 + q * 8;
  floatx4 acc[8];
#pragma unroll
  for (int n = 0; n < 8; n++) acc[n] = (floatx4){0.f, 0.f, 0.f, 0.f};

  const unsigned short* bbase = Bf + (size_t)f * 20480 + lane * 8;
#pragma unroll
  for (int kc = 0; kc < 5; kc++) {
    short8 a = *(const short8*)(pa + kc * 32);
#pragma unroll
    for (int n = 0; n < 8; n++) {
      short8 b = *(const short8*)(bbase + n * 2560 + kc * 512);
      acc[n] = __builtin_amdgcn_mfma_f32_16x16x32_bf16(a, b, acc[n], 0, 0, 0);
    }
  }

  // ---- LN1 with softmax fold: LN(x/s) == (x-mu)*rsqrt(var + eps*s^2) ----
  {
    float lw[8], lb[8];
#pragma unroll
    for (int n = 0; n < 8; n++) { lw[n] = ln1w[n * 16 + c]; lb[n] = ln1b[n * 16 + c]; }
#pragma unroll
    for (int rr = 0; rr < 4; rr++) {
      const int row = wv * 16 + q * 4 + rr;
      const float4 sv = *(const float4*)&sPT[row][0];   // one ds_read_b128
      float st = sv.x + sv.y + sv.z + sv.w;
      float s1 = 0.f, s2 = 0.f;
#pragma unroll
      for (int n = 0; n < 8; n++) { float v = acc[n][rr]; s1 += v; s2 += v * v; }
      s1 = rowsum16(s1);
      s2 = rowsum16(s2);
      float mu = s1 * (1.f / 128.f);
      float var = fmaxf(s2 * (1.f / 128.f) - mu * mu, 0.f);
      float rs = rsqrtf(var + GEPS * st * st);
#pragma unroll
      for (int n = 0; n < 8; n++)
        acc[n][rr] = (acc[n][rr] - mu) * rs * lw[n] + lb[n];
    }
  }

  // ---- Fn -> lsA (A-layout bf16, wave-private; no barrier needed) ----
#pragma unroll
  for (int rr = 0; rr < 4; rr++)
#pragma unroll
    for (int n = 0; n < 8; n++)
      lsA[(wv * 16 + q * 4 + rr) * 168 + n * 16 + c] =
          (unsigned short)f2bfu(acc[n][rr]);

  // ---- GEMM2: H = Fn[64x128] @ fc1w[128x128]  (kc-outer) ----
  {
    short8 a0 = *(const short8*)(pa);
    short8 a1 = *(const short8*)(pa + 32);
    short8 a2 = *(const short8*)(pa + 64);
    short8 a3 = *(const short8*)(pa + 96);
#pragma unroll
    for (int n = 0; n < 8; n++) acc[n] = (floatx4){0.f, 0.f, 0.f, 0.f};
    const unsigned short* w1p = W1f + lane * 8;
#pragma unroll
    for (int n = 0; n < 8; n++) {
      const unsigned short* wp = w1p + n * 2048;
      acc[n] = __builtin_amdgcn_mfma_f32_16x16x32_bf16(a0, *(const short8*)(wp),        acc[n], 0, 0, 0);
      acc[n] = __builtin_amdgcn_mfma_f32_16x16x32_bf16(a1, *(const short8*)(wp + 512),  acc[n], 0, 0, 0);
      acc[n] = __builtin_amdgcn_mfma_f32_16x16x32_bf16(a2, *(const short8*)(wp + 1024), acc[n], 0, 0, 0);
      acc[n] = __builtin_amdgcn_mfma_f32_16x16x32_bf16(a3, *(const short8*)(wp + 1536), acc[n], 0, 0, 0);
    }
  }

  // ---- bias + ReLU + LN2 (DPP row-reduce) ----
  {
    float fb[8], lw[8], lb[8];
#pragma unroll
    for (int n = 0; n < 8; n++) {
      fb[n] = fc1b[n * 16 + c];
      lw[n] = ln2w[n * 16 + c]; lb[n] = ln2b[n * 16 + c];
    }
#pragma unroll
    for (int rr = 0; rr < 4; rr++) {
#pragma unroll
      for (int n = 0; n < 8; n++) acc[n][rr] = fmaxf(acc[n][rr] + fb[n], 0.f);
      float s1 = 0.f, s2 = 0.f;
#pragma unroll
      for (int n = 0; n < 8; n++) { float v = acc[n][rr]; s1 += v; s2 += v * v; }
      s1 = rowsum16(s1);
      s2 = rowsum16(s2);
      float mu = s1 * (1.f / 128.f);
      float var = fmaxf(s2 * (1.f / 128.f) - mu * mu, 0.f);
      float rs = rsqrtf(var + GEPS);
#pragma unroll
      for (int n = 0; n < 8; n++)
        acc[n][rr] = (acc[n][rr] - mu) * rs * lw[n] + lb[n];
    }
  }

  // ---- H2 -> lsA (A-layout, wave-private; no barrier) ----
#pragma unroll
  for (int rr = 0; rr < 4; rr++)
#pragma unroll
    for (int n = 0; n < 8; n++)
      lsA[(wv * 16 + q * 4 + rr) * 168 + n * 16 + c] =
          (unsigned short)f2bfu(acc[n][rr]);

  // ---- fc2 (16-col padded tile) + mean-atomic ----
  floatx4 o4 = (floatx4){0.f, 0.f, 0.f, 0.f};
#pragma unroll
  for (int kc = 0; kc < 4; kc++) {
    short8 a = *(const short8*)(pa + kc * 32);
    short8 b = *(const short8*)(W2f + kc * 512 + lane * 8);
    o4 = __builtin_amdgcn_mfma_f32_16x16x32_bf16(a, b, o4, 0, 0, 0);
  }
  if (c < NCLS) {
    float bias = fc2b[c];
#pragma unroll
    for (int rr = 0; rr < 4; rr++)
      atomicAdd(out + (size_t)(b0 + wv * 16 + q * 4 + rr) * NCLS + c,
                (o4[rr] + bias) * 0.01f);
  }
}

// ---------------------------------------------------------------------------
extern "C" void kernel_launch(void* const* d_in, const int* in_sizes, int n_in,
                              void* d_out, int out_size, void* d_ws, size_t ws_size,
                              hipStream_t stream)
{
  (void)in_sizes; (void)n_in; (void)ws_size; (void)out_size;
  const float* x    = (const float*)d_in[0];
  const float* w1   = (const float*)d_in[1];
  const float* b1   = (const float*)d_in[2];
  const int*   perm = (const int*)d_in[3];
  const float* gn1w = (const float*)d_in[4];
  const float* gn1b = (const float*)d_in[5];
  const float* c2w  = (const float*)d_in[6];
  const float* c2b  = (const float*)d_in[7];
  const float* gn2w = (const float*)d_in[8];
  const float* gn2b = (const float*)d_in[9];
  const float* c3w  = (const float*)d_in[10];
  const float* c3b  = (const float*)d_in[11];
  const int*   swr  = (const int*)d_in[12];
  const float* E    = (const float*)d_in[13];
  const float* ln1w = (const float*)d_in[14];
  const float* ln1b = (const float*)d_in[15];
  const float* fc1w = (const float*)d_in[16];
  const float* fc1b = (const float*)d_in[17];
  const float* ln2w = (const float*)d_in[18];
  const float* ln2b = (const float*)d_in[19];
  const float* fc2w = (const float*)d_in[20];
  const float* fc2b = (const float*)d_in[21];
  float* out = (float*)d_out;

  // workspace layout:
  //   [0, 13.1MB)       : wT logits bf16 [1600][B]
  //   [13.1MB, +4.10MB) : Bf (100*20480 shorts)
  //   then W1f 32,768 B, W2f 4,096 B
  const size_t W_BYTES = (size_t)NB * NRODT * 2;     // 13,107,200
  unsigned short* wTbuf = (unsigned short*)d_ws;
  unsigned short* Bfb   = (unsigned short*)((char*)d_ws + W_BYTES);
  unsigned short* W1fb  = (unsigned short*)((char*)d_ws + W_BYTES + 4096000);
  unsigned short* W2fb  = (unsigned short*)((char*)d_ws + W_BYTES + 4096000 + 32768);

  k01_prep<<<1600 + NFOR + 2 + 3, 256, 0, stream>>>(
      x, w1, b1, perm, gn1w, gn1b, c2w, c2b, gn2w, gn2b, c3w, c3b,
      E, swr, fc1w, fc2w, wTbuf, Bfb, W1fb, W2fb, out);
  dim3 g3(NB / 64, NFOR);
  k3_mfma<<<g3, 256, 0, stream>>>(wTbuf, swr, Bfb, W1fb, W2fb,
                                  ln1w, ln1b, fc1b, ln2w, ln2b, fc2b, out);
}